// Round 5
// baseline (560.558 us; speedup 1.0000x reference)
//
#include <hip/hip_runtime.h>

#define NND 50000
#define NED 500000
#define F0 64
#define F1 128
#define NCLS 4
#define NG 8

#define NBLK 256
#define NTHR 256
#define TILE 96   // n2-nodes per LDS tile in the tail phase

// capacities (expected: n2~80, e3~80, e2~800, n1~800, e1~8000)
#define N1CAP 4096
#define N2CAP 1024
#define E1CAP 32768
#define E2CAP 8192
#define E3CAP 2048

// cnts: [0]=n1 [1]=n2 [2]=e1 [3]=e2 [4]=e3 ; bar: 8 barrier counters

__device__ __forceinline__ void load_targets(const int* __restrict__ tnode,
                                             const unsigned* __restrict__ bnn,
                                             int* t) {
    bool is64 = true;
    #pragma unroll
    for (int k = 0; k < 4; k++) if (bnn[2 * k + 1] != 0u) { is64 = false; break; }
    long long off = 0;
    #pragma unroll
    for (int g = 0; g < NG; g++) {
        t[g] = tnode[g] + (int)off;
        off += is64 ? (long long)bnn[2 * g] : (long long)(int)bnn[g];
    }
}

__device__ __forceinline__ int tgt_of(int d, const int* t) {
    int g = -1;
    #pragma unroll
    for (int k = 0; k < NG; k++) if (d == t[k]) g = k;
    return g;
}

// device-scope grid barrier; bar[i] pre-zeroed by k_init, used once per call
__device__ __forceinline__ void gbar(unsigned* bar, int i) {
    __threadfence();            // each wave drains its own stores (release)
    __syncthreads();
    if (threadIdx.x == 0) {
        atomicAdd(&bar[i], 1u);
        while (atomicAdd(&bar[i], 0u) < (unsigned)NBLK)
            __builtin_amdgcn_s_sleep(16);
        __threadfence();        // acquire: invalidate stale L1/L2 lines
    }
    __syncthreads();
}

// workspace init: zero region + 0xFF region, 16B stores
__global__ __launch_bounds__(256) void k_init(char* ws, unsigned zw, unsigned foff, unsigned fw) {
    unsigned t = blockIdx.x * blockDim.x + threadIdx.x;
    if (t < zw) ((uint4*)ws)[t] = make_uint4(0u, 0u, 0u, 0u);
    if (t < fw) ((uint4*)(ws + foff))[t] = make_uint4(~0u, ~0u, ~0u, ~0u);
}

__global__ __launch_bounds__(NTHR, 1) void k_main(
        const float* __restrict__ feat, const float* __restrict__ ew,
        const int* __restrict__ src, const int* __restrict__ dst,
        const int* __restrict__ tnode, const unsigned* __restrict__ bnn,
        const float* __restrict__ W1, const float* __restrict__ b1,
        const float* __restrict__ W2, const float* __restrict__ b2,
        const float* __restrict__ W3, const float* __restrict__ b3,
        float* out,
        int* idx1, int* idx2, int* node1, int* node2,
        int* list1, int* list2, int* list3,
        unsigned* cnts, unsigned* incnt, unsigned* outcnt,
        unsigned char* need_out, float* agg1c, float* h1c, unsigned* bar) {
    __shared__ unsigned s_le, s_ln, s_eb, s_nb;
    __shared__ float sagg3[NG * F1];
    __shared__ float sagg2[TILE * F1];
    __shared__ float sa[2 * F0];

    const int tid = threadIdx.x;
    const int gid = blockIdx.x * NTHR + tid;
    int tg[NG]; load_targets(tnode, bnn, tg);

    // ---- phase A: edges into targets (list3), claim node2, target in-deg ----
    {
        if (tid == 0) { s_le = 0; s_ln = 0; }
        __syncthreads();
        int base = gid * 8;
        bool eh[8] = {}, wn[8] = {};
        unsigned eo[8], no[8]; int sr[8];
        if (base < NED) {
            #pragma unroll
            for (int c = 0; c < 2; c++) {
                int4 d4 = *(const int4*)(dst + base + c * 4);
                int dd[4] = {d4.x, d4.y, d4.z, d4.w};
                #pragma unroll
                for (int k = 0; k < 4; k++) {
                    int q = c * 4 + k, d = dd[k];
                    if (tgt_of(d, tg) >= 0) {
                        eh[q] = true; eo[q] = atomicAdd(&s_le, 1u);
                        atomicAdd(&incnt[d], 1u);
                        int s = src[base + q];
                        need_out[s] = 1;
                        if (atomicCAS(&idx2[s], -1, -2) == -1) {
                            wn[q] = true; sr[q] = s; no[q] = atomicAdd(&s_ln, 1u);
                        }
                    }
                }
            }
        }
        __syncthreads();
        if (tid == 0) {
            s_eb = s_le ? atomicAdd(&cnts[4], s_le) : 0u;
            s_nb = s_ln ? atomicAdd(&cnts[1], s_ln) : 0u;
        }
        __syncthreads();
        #pragma unroll
        for (int q = 0; q < 8; q++) {
            if (eh[q]) { unsigned p = s_eb + eo[q]; if (p < E3CAP) list3[p] = base + q; }
            if (wn[q]) {
                unsigned id = s_nb + no[q];
                if (id < N2CAP) { node2[id] = sr[q]; idx2[sr[q]] = (int)id; }
                else idx2[sr[q]] = -1;
            }
        }
    }
    gbar(bar, 0);

    // ---- phase B: edges into node2 (list2), claim node1, node2 in-deg ----
    {
        if (tid == 0) { s_le = 0; s_ln = 0; }
        __syncthreads();
        int base = gid * 8;
        bool eh[8] = {}, wn[8] = {};
        unsigned eo[8], no[8]; int sr[8];
        if (base < NED) {
            #pragma unroll
            for (int c = 0; c < 2; c++) {
                int4 d4 = *(const int4*)(dst + base + c * 4);
                int dd[4] = {d4.x, d4.y, d4.z, d4.w};
                #pragma unroll
                for (int k = 0; k < 4; k++) {
                    int q = c * 4 + k, d = dd[k];
                    if (idx2[d] >= 0) {
                        eh[q] = true; eo[q] = atomicAdd(&s_le, 1u);
                        if (tgt_of(d, tg) < 0) atomicAdd(&incnt[d], 1u);
                        int s = src[base + q];
                        need_out[s] = 1;
                        if (atomicCAS(&idx1[s], -1, -2) == -1) {
                            wn[q] = true; sr[q] = s; no[q] = atomicAdd(&s_ln, 1u);
                        }
                    }
                }
            }
        }
        __syncthreads();
        if (tid == 0) {
            s_eb = s_le ? atomicAdd(&cnts[3], s_le) : 0u;
            s_nb = s_ln ? atomicAdd(&cnts[0], s_ln) : 0u;
        }
        __syncthreads();
        #pragma unroll
        for (int q = 0; q < 8; q++) {
            if (eh[q]) { unsigned p = s_eb + eo[q]; if (p < E2CAP) list2[p] = base + q; }
            if (wn[q]) {
                unsigned id = s_nb + no[q];
                if (id < N1CAP) { node1[id] = sr[q]; idx1[sr[q]] = (int)id; }
                else idx1[sr[q]] = -1;
            }
        }
    }
    gbar(bar, 1);

    // ---- phase C: edges into node1 (list1), node1-only in-deg ----
    {
        if (tid == 0) s_le = 0;
        __syncthreads();
        int base = gid * 8;
        bool eh[8] = {}; unsigned eo[8];
        if (base < NED) {
            #pragma unroll
            for (int c = 0; c < 2; c++) {
                int4 d4 = *(const int4*)(dst + base + c * 4);
                int dd[4] = {d4.x, d4.y, d4.z, d4.w};
                #pragma unroll
                for (int k = 0; k < 4; k++) {
                    int q = c * 4 + k, d = dd[k];
                    if (idx1[d] >= 0) {
                        eh[q] = true; eo[q] = atomicAdd(&s_le, 1u);
                        if (idx2[d] < 0 && tgt_of(d, tg) < 0) atomicAdd(&incnt[d], 1u);
                        need_out[src[base + q]] = 1;
                    }
                }
            }
        }
        __syncthreads();
        if (tid == 0) s_eb = s_le ? atomicAdd(&cnts[2], s_le) : 0u;
        __syncthreads();
        #pragma unroll
        for (int q = 0; q < 8; q++)
            if (eh[q]) { unsigned p = s_eb + eo[q]; if (p < E1CAP) list1[p] = base + q; }
    }
    gbar(bar, 2);

    // ---- phase D: filtered out-degree ----
    {
        int base = gid * 8;
        if (base < NED) {
            #pragma unroll
            for (int c = 0; c < 2; c++) {
                int4 s4 = *(const int4*)(src + base + c * 4);
                int ss[4] = {s4.x, s4.y, s4.z, s4.w};
                #pragma unroll
                for (int k = 0; k < 4; k++)
                    if (need_out[ss[k]]) atomicAdd(&outcnt[ss[k]], 1u);
            }
        }
    }
    gbar(bar, 3);

    // ---- phase E: agg1 (wave per edge) ----
    {
        unsigned e1 = cnts[2]; if (e1 > E1CAP) e1 = E1CAP;
        int lane = tid & 63;
        unsigned w = (unsigned)gid >> 6;
        const unsigned nw = (NBLK * NTHR) >> 6;
        for (unsigned i = w; i < e1; i += nw) {
            int e = list1[i];
            int s = src[e], d = dst[e];
            int i1 = idx1[d]; if (i1 < 0) continue;
            float wt = ew[e] * rsqrtf(fmaxf((float)outcnt[s], 1.f));
            atomicAdd(&agg1c[(size_t)i1 * F0 + lane], feat[(size_t)s * F0 + lane] * wt);
        }
    }
    gbar(bar, 4);

    // ---- phase F: h1 = relu(in_norm*agg1 @ W1 + b1), 2 nodes/block-iter ----
    {
        unsigned n1 = cnts[0]; if (n1 > N1CAP) n1 = N1CAP;
        int sub = tid >> 7, j = tid & 127;
        unsigned iters = (n1 + NBLK * 2 - 1) / (NBLK * 2);
        for (unsigned it = 0; it < iters; it++) {
            unsigned i = it * NBLK * 2 + blockIdx.x * 2 + sub;
            bool act = i < n1;
            if (act && j < F0) {
                int v = node1[i];
                float innorm = rsqrtf(fmaxf((float)incnt[v], 1.f));
                sa[sub * F0 + j] = agg1c[(size_t)i * F0 + j] * innorm;
            }
            __syncthreads();
            if (act) {
                float acc = b1[j];
                #pragma unroll
                for (int k = 0; k < F0; k++) acc += sa[sub * F0 + k] * W1[k * F1 + j];
                h1c[(size_t)i * F1 + j] = fmaxf(acc, 0.f);
            }
            __syncthreads();
        }
    }
    gbar(bar, 5);

    if (blockIdx.x != 0) return;

    // ---- tail (block 0 only): agg2 -> h2 (in-place) -> agg3 -> out, all LDS ----
    {
        unsigned n2 = cnts[1]; if (n2 > N2CAP) n2 = N2CAP;
        unsigned e2 = cnts[3]; if (e2 > E2CAP) e2 = E2CAP;
        unsigned e3 = cnts[4]; if (e3 > E3CAP) e3 = E3CAP;
        int sub = tid >> 7, j = tid & 127;
        for (int t = tid; t < NG * F1; t += NTHR) sagg3[t] = 0.f;
        __syncthreads();

        for (unsigned t0 = 0; t0 < n2; t0 += TILE) {
            unsigned tlen = n2 - t0; if (tlen > TILE) tlen = TILE;
            for (unsigned t = tid; t < tlen * F1; t += NTHR) sagg2[t] = 0.f;
            __syncthreads();
            // agg2 into LDS tile
            for (unsigned ii = (unsigned)sub; ii < e2; ii += 2) {
                int e = list2[ii];
                int s = src[e], d = dst[e];
                int i1 = idx1[s]; if (i1 < 0) continue;
                unsigned i2 = (unsigned)idx2[d];
                if (i2 - t0 < tlen) {
                    float wt = ew[e] * rsqrtf(fmaxf((float)outcnt[s], 1.f));
                    atomicAdd(&sagg2[(i2 - t0) * F1 + j], h1c[(size_t)i1 * F1 + j] * wt);
                }
            }
            __syncthreads();
            // h2 in place, row pairs
            for (unsigned r0 = 0; r0 < tlen; r0 += 2) {
                unsigned r = r0 + (unsigned)sub;
                bool act = r < tlen;
                float acc = 0.f;
                if (act) {
                    int v = node2[t0 + r];
                    float innorm = rsqrtf(fmaxf((float)incnt[v], 1.f));
                    float dotv = 0.f;
                    #pragma unroll 32
                    for (int k = 0; k < F1; k++) dotv += sagg2[r * F1 + k] * W2[k * F1 + j];
                    acc = fmaxf(dotv * innorm + b2[j], 0.f);
                }
                __syncthreads();
                if (act) sagg2[r * F1 + j] = acc;
                __syncthreads();
            }
            // agg3 contributions from this tile
            for (unsigned ii = (unsigned)sub; ii < e3; ii += 2) {
                int e = list3[ii];
                int s = src[e];
                unsigned i2 = (unsigned)idx2[s];
                if (i2 - t0 >= tlen) continue;
                int d = dst[e];
                int g = tgt_of(d, tg);
                float wt = ew[e] * rsqrtf(fmaxf((float)outcnt[s], 1.f));
                atomicAdd(&sagg3[g * F1 + j], sagg2[(i2 - t0) * F1 + j] * wt);
            }
            __syncthreads();
        }
        if (tid < NG * NCLS) {
            int g = tid >> 2, c = tid & 3;
            float innorm = rsqrtf(fmaxf((float)incnt[tg[g]], 1.f));
            float sm = 0.f;
            for (int k = 0; k < F1; k++) sm += sagg3[g * F1 + k] * W3[k * NCLS + c];
            out[tid] = sm * innorm + b3[c];
        }
    }
}

extern "C" void kernel_launch(void* const* d_in, const int* in_sizes, int n_in,
                              void* d_out, int out_size, void* d_ws, size_t ws_size,
                              hipStream_t stream) {
    const float* in_feat = (const float*)d_in[0];
    const float* ew      = (const float*)d_in[1];
    const int*   src     = (const int*)d_in[2];
    const int*   dst     = (const int*)d_in[3];
    const unsigned* bnn  = (const unsigned*)d_in[4];
    const int*   tnode   = (const int*)d_in[5];
    const float* W1 = (const float*)d_in[6];
    const float* b1 = (const float*)d_in[7];
    const float* W2 = (const float*)d_in[8];
    const float* b2 = (const float*)d_in[9];
    const float* W3 = (const float*)d_in[10];
    const float* b3 = (const float*)d_in[11];
    float* out = (float*)d_out;
    (void)in_sizes; (void)n_in; (void)out_size; (void)ws_size;

    char* ws = (char*)d_ws;
    size_t o = 0;
    auto alloc = [&](size_t bytes) { size_t r = o; o += (bytes + 255) & ~(size_t)255; return r; };

    // --- zero-init region (starts at 0) ---
    size_t off_outcnt = alloc((size_t)NND * 4);
    size_t off_incnt  = alloc((size_t)NND * 4);
    size_t off_cnts   = alloc(8 * 4);
    size_t off_bar    = alloc(8 * 4);
    size_t off_agg1   = alloc((size_t)N1CAP * F0 * 4);
    size_t off_need   = alloc((size_t)NND);
    size_t zero_bytes = o;
    // --- 0xFF-init region ---
    size_t ff_start = o;
    size_t off_idx2   = alloc((size_t)NND * 4);
    size_t off_idx1   = alloc((size_t)NND * 4);
    size_t ff_bytes = o - ff_start;
    // --- write-before-read region ---
    size_t off_node2   = alloc((size_t)N2CAP * 4);
    size_t off_node1   = alloc((size_t)N1CAP * 4);
    size_t off_list3   = alloc((size_t)E3CAP * 4);
    size_t off_list2   = alloc((size_t)E2CAP * 4);
    size_t off_list1   = alloc((size_t)E1CAP * 4);
    size_t off_h1      = alloc((size_t)N1CAP * F1 * 4);

    unsigned* outcnt  = (unsigned*)(ws + off_outcnt);
    unsigned* incnt   = (unsigned*)(ws + off_incnt);
    unsigned* cnts    = (unsigned*)(ws + off_cnts);
    unsigned* bar     = (unsigned*)(ws + off_bar);
    float*    agg1c   = (float*)(ws + off_agg1);
    unsigned char* need_out = (unsigned char*)(ws + off_need);
    int*      idx2    = (int*)(ws + off_idx2);
    int*      idx1    = (int*)(ws + off_idx1);
    int*      node2   = (int*)(ws + off_node2);
    int*      node1   = (int*)(ws + off_node1);
    int*      list3   = (int*)(ws + off_list3);
    int*      list2   = (int*)(ws + off_list2);
    int*      list1   = (int*)(ws + off_list1);
    float*    h1c     = (float*)(ws + off_h1);

    unsigned zw = (unsigned)(zero_bytes / 16);
    unsigned fw = (unsigned)(ff_bytes / 16);
    unsigned iw = zw > fw ? zw : fw;
    k_init<<<(iw + 255) / 256, 256, 0, stream>>>(ws, zw, (unsigned)ff_start, fw);

    k_main<<<NBLK, NTHR, 0, stream>>>(in_feat, ew, src, dst, tnode, bnn,
                                      W1, b1, W2, b2, W3, b3, out,
                                      idx1, idx2, node1, node2,
                                      list1, list2, list3,
                                      cnts, incnt, outcnt, need_out,
                                      agg1c, h1c, bar);
}

// Round 6
// 262.508 us; speedup vs baseline: 2.1354x; 2.1354x over previous
//
#include <hip/hip_runtime.h>

#define NND 50000
#define NED 500000
#define F0 64
#define F1 128
#define NCLS 4
#define NG 8

#define NBLK 128
#define NTHR 256
#define EPT 16          // edges per thread in full scans (NBLK*NTHR*EPT = 524288 >= NED)
#define NBAR 9
#define STG 4096        // per-block edge-hit staging (= NTHR*EPT worst case)
#define STGN 1024       // per-block node-claim staging

// capacities (expected: n2~80, e3~80, e2~800, n1~800, e1~8000)
#define N1CAP 4096
#define N2CAP 1024
#define E1CAP 32768
#define E2CAP 8192
#define E3CAP 2048

// cnts: [0]=n1 [1]=n2 [2]=e1 [3]=e2 [4]=e3

__device__ __forceinline__ void load_targets(const int* __restrict__ tnode,
                                             const unsigned* __restrict__ bnn,
                                             int* t) {
    bool is64 = true;
    #pragma unroll
    for (int k = 0; k < 4; k++) if (bnn[2 * k + 1] != 0u) { is64 = false; break; }
    long long off = 0;
    #pragma unroll
    for (int g = 0; g < NG; g++) {
        t[g] = tnode[g] + (int)off;
        off += is64 ? (long long)bnn[2 * g] : (long long)(int)bnn[g];
    }
}

__device__ __forceinline__ int tgt_of(int d, const int* t) {
    int g = -1;
    #pragma unroll
    for (int k = 0; k < NG; k++) if (d == t[k]) g = k;
    return g;
}

// grid barrier: arrival = one RMW per block; wait = relaxed atomic LOAD poll
// (no RMW storm — R5's atomicAdd(p,0) polling was the 100us/barrier killer).
// bar counters 128B apart, pre-zeroed by k_init, each used once per launch.
__device__ __forceinline__ void gbar(unsigned* bar, int i) {
    __threadfence();                 // release: drain stores to coherence point
    __syncthreads();
    if (threadIdx.x == 0) {
        unsigned* p = bar + i * 32;
        atomicAdd(p, 1u);
        while (__hip_atomic_load(p, __ATOMIC_RELAXED, __HIP_MEMORY_SCOPE_AGENT)
               < (unsigned)NBLK)
            __builtin_amdgcn_s_sleep(1);
    }
    __syncthreads();
    __threadfence();                 // acquire: all threads invalidate stale lines
}

// workspace init: zero region + 0xFF region, 16B stores
__global__ __launch_bounds__(256) void k_init(char* ws, unsigned zw, unsigned foff, unsigned fw) {
    unsigned t = blockIdx.x * blockDim.x + threadIdx.x;
    if (t < zw) ((uint4*)ws)[t] = make_uint4(0u, 0u, 0u, 0u);
    if (t < fw) ((uint4*)(ws + foff))[t] = make_uint4(~0u, ~0u, ~0u, ~0u);
}

__global__ __launch_bounds__(NTHR, 1) void k_main(
        const float* __restrict__ feat, const float* __restrict__ ew,
        const int* __restrict__ src, const int* __restrict__ dst,
        const int* __restrict__ tnode, const unsigned* __restrict__ bnn,
        const float* __restrict__ W1, const float* __restrict__ b1,
        const float* __restrict__ W2, const float* __restrict__ b2,
        const float* __restrict__ W3, const float* __restrict__ b3,
        float* out,
        int* idx1, int* idx2, int* node1, int* node2,
        int* list1, int* list2, int* list3,
        unsigned* cnts, unsigned* incnt, unsigned* outcnt,
        unsigned char* need_out, float* agg1c, float* agg2c, float* agg3g,
        float* h1c, float* h2c, unsigned* bar) {
    __shared__ unsigned s_le, s_ln, s_eb, s_nb;
    __shared__ int stage[STG];
    __shared__ int stageN[STGN];
    __shared__ float sa[2 * F1];

    const int tid = threadIdx.x;
    const int gid = blockIdx.x * NTHR + tid;
    int tg[NG]; load_targets(tnode, bnn, tg);

    // ---- phase A: edges into targets -> list3; claim node2; target in-deg ----
    {
        if (tid == 0) { s_le = 0; s_ln = 0; }
        __syncthreads();
        int base = gid * EPT;
        if (base < NED) {
            #pragma unroll
            for (int c = 0; c < EPT / 4; c++) {
                int4 d4 = *(const int4*)(dst + base + c * 4);
                int dd[4] = {d4.x, d4.y, d4.z, d4.w};
                #pragma unroll
                for (int k = 0; k < 4; k++) {
                    int d = dd[k];
                    if (tgt_of(d, tg) >= 0) {
                        stage[atomicAdd(&s_le, 1u)] = base + c * 4 + k;
                        atomicAdd(&incnt[d], 1u);
                        int s = src[base + c * 4 + k];
                        need_out[s] = 1;
                        if (atomicCAS(&idx2[s], -1, -2) == -1) {
                            unsigned n = atomicAdd(&s_ln, 1u);
                            if (n < STGN) stageN[n] = s; else idx2[s] = -1;
                        }
                    }
                }
            }
        }
        __syncthreads();
        if (tid == 0) {
            s_eb = s_le ? atomicAdd(&cnts[4], s_le) : 0u;
            s_nb = s_ln ? atomicAdd(&cnts[1], s_ln) : 0u;
        }
        __syncthreads();
        for (unsigned t = tid; t < s_le; t += NTHR) {
            unsigned p = s_eb + t; if (p < E3CAP) list3[p] = stage[t];
        }
        unsigned ln = s_ln < STGN ? s_ln : STGN;
        for (unsigned t = tid; t < ln; t += NTHR) {
            int s = stageN[t]; unsigned id = s_nb + t;
            if (id < N2CAP) { node2[id] = s; idx2[s] = (int)id; } else idx2[s] = -1;
        }
    }
    gbar(bar, 0);

    // ---- phase B: edges into node2 -> list2; claim node1; node2 in-deg ----
    {
        if (tid == 0) { s_le = 0; s_ln = 0; }
        __syncthreads();
        int base = gid * EPT;
        if (base < NED) {
            #pragma unroll
            for (int c = 0; c < EPT / 4; c++) {
                int4 d4 = *(const int4*)(dst + base + c * 4);
                int dd[4] = {d4.x, d4.y, d4.z, d4.w};
                #pragma unroll
                for (int k = 0; k < 4; k++) {
                    int d = dd[k];
                    if (idx2[d] >= 0) {
                        stage[atomicAdd(&s_le, 1u)] = base + c * 4 + k;
                        if (tgt_of(d, tg) < 0) atomicAdd(&incnt[d], 1u);
                        int s = src[base + c * 4 + k];
                        need_out[s] = 1;
                        if (atomicCAS(&idx1[s], -1, -2) == -1) {
                            unsigned n = atomicAdd(&s_ln, 1u);
                            if (n < STGN) stageN[n] = s; else idx1[s] = -1;
                        }
                    }
                }
            }
        }
        __syncthreads();
        if (tid == 0) {
            s_eb = s_le ? atomicAdd(&cnts[3], s_le) : 0u;
            s_nb = s_ln ? atomicAdd(&cnts[0], s_ln) : 0u;
        }
        __syncthreads();
        for (unsigned t = tid; t < s_le; t += NTHR) {
            unsigned p = s_eb + t; if (p < E2CAP) list2[p] = stage[t];
        }
        unsigned ln = s_ln < STGN ? s_ln : STGN;
        for (unsigned t = tid; t < ln; t += NTHR) {
            int s = stageN[t]; unsigned id = s_nb + t;
            if (id < N1CAP) { node1[id] = s; idx1[s] = (int)id; } else idx1[s] = -1;
        }
    }
    gbar(bar, 1);

    // ---- phase C: edges into node1 -> list1; node1-only in-deg ----
    {
        if (tid == 0) s_le = 0;
        __syncthreads();
        int base = gid * EPT;
        if (base < NED) {
            #pragma unroll
            for (int c = 0; c < EPT / 4; c++) {
                int4 d4 = *(const int4*)(dst + base + c * 4);
                int dd[4] = {d4.x, d4.y, d4.z, d4.w};
                #pragma unroll
                for (int k = 0; k < 4; k++) {
                    int d = dd[k];
                    if (idx1[d] >= 0) {
                        stage[atomicAdd(&s_le, 1u)] = base + c * 4 + k;
                        if (idx2[d] < 0 && tgt_of(d, tg) < 0) atomicAdd(&incnt[d], 1u);
                        need_out[src[base + c * 4 + k]] = 1;
                    }
                }
            }
        }
        __syncthreads();
        if (tid == 0) s_eb = s_le ? atomicAdd(&cnts[2], s_le) : 0u;
        __syncthreads();
        for (unsigned t = tid; t < s_le; t += NTHR) {
            unsigned p = s_eb + t; if (p < E1CAP) list1[p] = stage[t];
        }
    }
    gbar(bar, 2);

    // ---- phase D: filtered out-degree ----
    {
        int base = gid * EPT;
        if (base < NED) {
            #pragma unroll
            for (int c = 0; c < EPT / 4; c++) {
                int4 s4 = *(const int4*)(src + base + c * 4);
                int ss[4] = {s4.x, s4.y, s4.z, s4.w};
                #pragma unroll
                for (int k = 0; k < 4; k++)
                    if (need_out[ss[k]]) atomicAdd(&outcnt[ss[k]], 1u);
            }
        }
    }
    gbar(bar, 3);

    // ---- phase E: agg1 (one 64-lane wave per edge) ----
    {
        unsigned e1 = cnts[2]; if (e1 > E1CAP) e1 = E1CAP;
        int lane = tid & 63;
        unsigned w = (unsigned)gid >> 6;
        const unsigned nw = (NBLK * NTHR) >> 6;
        for (unsigned i = w; i < e1; i += nw) {
            int e = list1[i];
            int s = src[e], d = dst[e];
            int i1 = idx1[d]; if (i1 < 0) continue;
            float wt = ew[e] * rsqrtf(fmaxf((float)outcnt[s], 1.f));
            atomicAdd(&agg1c[(size_t)i1 * F0 + lane], feat[(size_t)s * F0 + lane] * wt);
        }
    }
    gbar(bar, 4);

    // ---- phase F: h1 = relu(in_norm*agg1 @ W1 + b1), 2 nodes per block-iter ----
    {
        unsigned n1 = cnts[0]; if (n1 > N1CAP) n1 = N1CAP;
        int sub = tid >> 7, j = tid & 127;
        unsigned iters = (n1 + NBLK * 2 - 1) / (NBLK * 2);
        for (unsigned it = 0; it < iters; it++) {
            unsigned i = it * NBLK * 2 + blockIdx.x * 2 + sub;
            bool act = i < n1;
            if (act && j < F0) {
                int v = node1[i];
                float innorm = rsqrtf(fmaxf((float)incnt[v], 1.f));
                sa[sub * F0 + j] = agg1c[(size_t)i * F0 + j] * innorm;
            }
            __syncthreads();
            if (act) {
                float acc = b1[j];
                #pragma unroll
                for (int k = 0; k < F0; k++) acc += sa[sub * F0 + k] * W1[k * F1 + j];
                h1c[(size_t)i * F1 + j] = fmaxf(acc, 0.f);
            }
            __syncthreads();
        }
    }
    gbar(bar, 5);

    // ---- phase G: agg2 (128-thread group per edge) ----
    {
        unsigned e2 = cnts[3]; if (e2 > E2CAP) e2 = E2CAP;
        int j = tid & 127;
        unsigned grp = (unsigned)gid >> 7;
        const unsigned ng = (NBLK * NTHR) >> 7;
        for (unsigned i = grp; i < e2; i += ng) {
            int e = list2[i];
            int s = src[e], d = dst[e];
            int i1 = idx1[s], i2 = idx2[d];
            if (i1 < 0 || i2 < 0) continue;
            float wt = ew[e] * rsqrtf(fmaxf((float)outcnt[s], 1.f));
            atomicAdd(&agg2c[(size_t)i2 * F1 + j], h1c[(size_t)i1 * F1 + j] * wt);
        }
    }
    gbar(bar, 6);

    // ---- phase H: h2 = relu(in_norm*agg2 @ W2 + b2), 2 nodes per block-iter ----
    {
        unsigned n2 = cnts[1]; if (n2 > N2CAP) n2 = N2CAP;
        int sub = tid >> 7, j = tid & 127;
        unsigned iters = (n2 + NBLK * 2 - 1) / (NBLK * 2);
        for (unsigned it = 0; it < iters; it++) {
            unsigned i = it * NBLK * 2 + blockIdx.x * 2 + sub;
            bool act = i < n2;
            if (act) {
                int v = node2[i];
                float innorm = rsqrtf(fmaxf((float)incnt[v], 1.f));
                sa[sub * F1 + j] = agg2c[(size_t)i * F1 + j] * innorm;
            }
            __syncthreads();
            if (act) {
                float acc = 0.f;
                #pragma unroll 32
                for (int k = 0; k < F1; k++) acc += sa[sub * F1 + k] * W2[k * F1 + j];
                h2c[(size_t)i * F1 + j] = fmaxf(acc + b2[j], 0.f);
            }
            __syncthreads();
        }
    }
    gbar(bar, 7);

    // ---- phase I: agg3 into global agg3g (128-thread group per edge) ----
    {
        unsigned e3 = cnts[4]; if (e3 > E3CAP) e3 = E3CAP;
        int j = tid & 127;
        unsigned grp = (unsigned)gid >> 7;
        const unsigned ng = (NBLK * NTHR) >> 7;
        for (unsigned i = grp; i < e3; i += ng) {
            int e = list3[i];
            int s = src[e], d = dst[e];
            int i2 = idx2[s]; if (i2 < 0) continue;
            int g = tgt_of(d, tg);
            float wt = ew[e] * rsqrtf(fmaxf((float)outcnt[s], 1.f));
            atomicAdd(&agg3g[(size_t)g * F1 + j], h2c[(size_t)i2 * F1 + j] * wt);
        }
    }
    gbar(bar, 8);

    // ---- phase J: final 8x4 output (block 0) ----
    if (blockIdx.x == 0 && tid < NG * NCLS) {
        int g = tid >> 2, c = tid & 3;
        float innorm = rsqrtf(fmaxf((float)incnt[tg[g]], 1.f));
        float sm = 0.f;
        #pragma unroll 32
        for (int k = 0; k < F1; k++) sm += agg3g[g * F1 + k] * W3[k * NCLS + c];
        out[tid] = sm * innorm + b3[c];
    }
}

extern "C" void kernel_launch(void* const* d_in, const int* in_sizes, int n_in,
                              void* d_out, int out_size, void* d_ws, size_t ws_size,
                              hipStream_t stream) {
    const float* in_feat = (const float*)d_in[0];
    const float* ew      = (const float*)d_in[1];
    const int*   src     = (const int*)d_in[2];
    const int*   dst     = (const int*)d_in[3];
    const unsigned* bnn  = (const unsigned*)d_in[4];
    const int*   tnode   = (const int*)d_in[5];
    const float* W1 = (const float*)d_in[6];
    const float* b1 = (const float*)d_in[7];
    const float* W2 = (const float*)d_in[8];
    const float* b2 = (const float*)d_in[9];
    const float* W3 = (const float*)d_in[10];
    const float* b3 = (const float*)d_in[11];
    float* out = (float*)d_out;
    (void)in_sizes; (void)n_in; (void)out_size; (void)ws_size;

    char* ws = (char*)d_ws;
    size_t o = 0;
    auto alloc = [&](size_t bytes) { size_t r = o; o += (bytes + 255) & ~(size_t)255; return r; };

    // --- zero-init region (starts at 0) ---
    size_t off_outcnt = alloc((size_t)NND * 4);
    size_t off_incnt  = alloc((size_t)NND * 4);
    size_t off_cnts   = alloc(8 * 4);
    size_t off_bar    = alloc((size_t)NBAR * 32 * 4);
    size_t off_agg1   = alloc((size_t)N1CAP * F0 * 4);
    size_t off_agg2   = alloc((size_t)N2CAP * F1 * 4);
    size_t off_agg3   = alloc((size_t)NG * F1 * 4);
    size_t off_need   = alloc((size_t)NND);
    size_t zero_bytes = o;
    // --- 0xFF-init region ---
    size_t ff_start = o;
    size_t off_idx2   = alloc((size_t)NND * 4);
    size_t off_idx1   = alloc((size_t)NND * 4);
    size_t ff_bytes = o - ff_start;
    // --- write-before-read region ---
    size_t off_node2   = alloc((size_t)N2CAP * 4);
    size_t off_node1   = alloc((size_t)N1CAP * 4);
    size_t off_list3   = alloc((size_t)E3CAP * 4);
    size_t off_list2   = alloc((size_t)E2CAP * 4);
    size_t off_list1   = alloc((size_t)E1CAP * 4);
    size_t off_h1      = alloc((size_t)N1CAP * F1 * 4);
    size_t off_h2      = alloc((size_t)N2CAP * F1 * 4);

    unsigned* outcnt  = (unsigned*)(ws + off_outcnt);
    unsigned* incnt   = (unsigned*)(ws + off_incnt);
    unsigned* cnts    = (unsigned*)(ws + off_cnts);
    unsigned* bar     = (unsigned*)(ws + off_bar);
    float*    agg1c   = (float*)(ws + off_agg1);
    float*    agg2c   = (float*)(ws + off_agg2);
    float*    agg3g   = (float*)(ws + off_agg3);
    unsigned char* need_out = (unsigned char*)(ws + off_need);
    int*      idx2    = (int*)(ws + off_idx2);
    int*      idx1    = (int*)(ws + off_idx1);
    int*      node2   = (int*)(ws + off_node2);
    int*      node1   = (int*)(ws + off_node1);
    int*      list3   = (int*)(ws + off_list3);
    int*      list2   = (int*)(ws + off_list2);
    int*      list1   = (int*)(ws + off_list1);
    float*    h1c     = (float*)(ws + off_h1);
    float*    h2c     = (float*)(ws + off_h2);

    unsigned zw = (unsigned)(zero_bytes / 16);
    unsigned fw = (unsigned)(ff_bytes / 16);
    unsigned iw = zw > fw ? zw : fw;
    k_init<<<(iw + 255) / 256, 256, 0, stream>>>(ws, zw, (unsigned)ff_start, fw);

    k_main<<<NBLK, NTHR, 0, stream>>>(in_feat, ew, src, dst, tnode, bnn,
                                      W1, b1, W2, b2, W3, b3, out,
                                      idx1, idx2, node1, node2,
                                      list1, list2, list3,
                                      cnts, incnt, outcnt, need_out,
                                      agg1c, agg2c, agg3g, h1c, h2c, bar);
}

// Round 7
// 78.521 us; speedup vs baseline: 7.1389x; 3.3431x over previous
//
#include <hip/hip_runtime.h>

#define NND 50000
#define NED 500000
#define F0 64
#define F1 128
#define NCLS 4
#define NG 8

#define NBLK 256
#define NTHR 256
#define EPT 8           // edges per thread (NBLK*NTHR*EPT = 524288 >= NED)
#define NBAR 8
#define NSUB 8          // arrival sub-counters per barrier
#define STG 2048        // per-block edge-hit staging (= NTHR*EPT worst case)
#define STGN 1024

// capacities (expected: n2~80, e3~80, e2~800, n1~800, e1~8000)
#define N1CAP 4096
#define N2CAP 1024
#define E1CAP 32768
#define E2CAP 8192
#define E3CAP 2048

// cnts: [0]=n1 [1]=n2 [2]=e1 [3]=e2 [4]=e3

// write-through store: bypasses non-coherent per-XCD L2 (sc-flagged), so
// cross-phase readers on other XCDs see it without any cache flush.
template <typename T>
__device__ __forceinline__ void st_wt(T* p, T v) {
    __hip_atomic_store(p, v, __ATOMIC_RELAXED, __HIP_MEMORY_SCOPE_AGENT);
}

__device__ __forceinline__ void load_targets(const int* __restrict__ tnode,
                                             const unsigned* __restrict__ bnn,
                                             int* t) {
    bool is64 = true;
    #pragma unroll
    for (int k = 0; k < 4; k++) if (bnn[2 * k + 1] != 0u) { is64 = false; break; }
    long long off = 0;
    #pragma unroll
    for (int g = 0; g < NG; g++) {
        t[g] = tnode[g] + (int)off;
        off += is64 ? (long long)bnn[2 * g] : (long long)(int)bnn[g];
    }
}

__device__ __forceinline__ int tgt_of(int d, const int* t) {
    int g = -1;
    #pragma unroll
    for (int k = 0; k < NG; k++) if (d == t[k]) g = k;
    return g;
}

// Fence-free grid barrier. All cross-phase data is write-through (st_wt /
// HW atomics), and __syncthreads drains each wave's vmcnt before s_barrier,
// so arrival implies data visibility — no buffer_wbl2/inv (R6's 25us/barrier
// cost). Two-level arrival spreads RMW contention over NSUB lines.
__device__ __forceinline__ void gbar(unsigned* bar, int i) {
    asm volatile("s_waitcnt vmcnt(0)" ::: "memory");
    __syncthreads();
    if (threadIdx.x == 0) {
        unsigned* sp = bar + (size_t)(i * (NSUB + 1) + (blockIdx.x & (NSUB - 1))) * 32;
        unsigned* mp = bar + (size_t)(i * (NSUB + 1) + NSUB) * 32;
        unsigned old = __hip_atomic_fetch_add(sp, 1u, __ATOMIC_RELAXED,
                                              __HIP_MEMORY_SCOPE_AGENT);
        if (old + 1u == (unsigned)(NBLK / NSUB))
            __hip_atomic_fetch_add(mp, 1u, __ATOMIC_RELAXED, __HIP_MEMORY_SCOPE_AGENT);
        while (__hip_atomic_load(mp, __ATOMIC_RELAXED, __HIP_MEMORY_SCOPE_AGENT)
               < (unsigned)NSUB)
            __builtin_amdgcn_s_sleep(2);
    }
    __syncthreads();
}

// workspace init: zero region + 0xFF region, 16B stores
__global__ __launch_bounds__(256) void k_init(char* ws, unsigned zw, unsigned foff, unsigned fw) {
    unsigned t = blockIdx.x * blockDim.x + threadIdx.x;
    if (t < zw) ((uint4*)ws)[t] = make_uint4(0u, 0u, 0u, 0u);
    if (t < fw) ((uint4*)(ws + foff))[t] = make_uint4(~0u, ~0u, ~0u, ~0u);
}

__global__ __launch_bounds__(NTHR, 1) void k_main(
        const float* __restrict__ feat, const float* __restrict__ ew,
        const int* __restrict__ src, const int* __restrict__ dst,
        const int* __restrict__ tnode, const unsigned* __restrict__ bnn,
        const float* __restrict__ W1, const float* __restrict__ b1,
        const float* __restrict__ W2, const float* __restrict__ b2,
        const float* __restrict__ W3, const float* __restrict__ b3,
        float* out,
        int* idx1, int* idx2, int* node1, int* node2,
        int* list1, int* list2, int* list3,
        unsigned* cnts, unsigned* incnt, unsigned* outcnt,
        unsigned char* need_out, float* agg1c, float* agg2c,
        float* h1c, float* h2c, unsigned* bar) {
    __shared__ unsigned s_le, s_ln, s_eb, s_nb;
    __shared__ int stage[STG];
    __shared__ int stageN[STGN];
    __shared__ float sa[2 * F1];

    const int tid = threadIdx.x;
    const int gid = blockIdx.x * NTHR + tid;
    int tg[NG]; load_targets(tnode, bnn, tg);

    // ---- phase A: edges into targets -> list3; claim node2; target in-deg ----
    {
        if (tid == 0) { s_le = 0; s_ln = 0; }
        __syncthreads();
        int base = gid * EPT;
        if (base < NED) {
            #pragma unroll
            for (int c = 0; c < EPT / 4; c++) {
                int4 d4 = *(const int4*)(dst + base + c * 4);
                int dd[4] = {d4.x, d4.y, d4.z, d4.w};
                #pragma unroll
                for (int k = 0; k < 4; k++) {
                    int d = dd[k];
                    if (tgt_of(d, tg) >= 0) {
                        stage[atomicAdd(&s_le, 1u)] = base + c * 4 + k;
                        atomicAdd(&incnt[d], 1u);
                        int s = src[base + c * 4 + k];
                        st_wt(&need_out[s], (unsigned char)1);
                        if (atomicCAS(&idx2[s], -1, -2) == -1) {
                            unsigned n = atomicAdd(&s_ln, 1u);
                            if (n < STGN) stageN[n] = s; else st_wt(&idx2[s], -1);
                        }
                    }
                }
            }
        }
        __syncthreads();
        if (tid == 0) {
            s_eb = s_le ? atomicAdd(&cnts[4], s_le) : 0u;
            s_nb = s_ln ? atomicAdd(&cnts[1], s_ln) : 0u;
        }
        __syncthreads();
        for (unsigned t = tid; t < s_le; t += NTHR) {
            unsigned p = s_eb + t; if (p < E3CAP) st_wt(&list3[p], stage[t]);
        }
        unsigned ln = s_ln < STGN ? s_ln : STGN;
        for (unsigned t = tid; t < ln; t += NTHR) {
            int s = stageN[t]; unsigned id = s_nb + t;
            if (id < N2CAP) { st_wt(&node2[id], s); st_wt(&idx2[s], (int)id); }
            else st_wt(&idx2[s], -1);
        }
        // pre-init out = b3 (accumulated into by phase I)
        if (blockIdx.x == 0 && tid < NG * NCLS) st_wt(&out[tid], b3[tid & 3]);
    }
    gbar(bar, 0);

    // ---- phase B: edges into node2 -> list2; claim node1; node2 in-deg ----
    {
        if (tid == 0) { s_le = 0; s_ln = 0; }
        __syncthreads();
        int base = gid * EPT;
        if (base < NED) {
            #pragma unroll
            for (int c = 0; c < EPT / 4; c++) {
                int4 d4 = *(const int4*)(dst + base + c * 4);
                int dd[4] = {d4.x, d4.y, d4.z, d4.w};
                #pragma unroll
                for (int k = 0; k < 4; k++) {
                    int d = dd[k];
                    if (idx2[d] >= 0) {
                        stage[atomicAdd(&s_le, 1u)] = base + c * 4 + k;
                        if (tgt_of(d, tg) < 0) atomicAdd(&incnt[d], 1u);
                        int s = src[base + c * 4 + k];
                        st_wt(&need_out[s], (unsigned char)1);
                        if (atomicCAS(&idx1[s], -1, -2) == -1) {
                            unsigned n = atomicAdd(&s_ln, 1u);
                            if (n < STGN) stageN[n] = s; else st_wt(&idx1[s], -1);
                        }
                    }
                }
            }
        }
        __syncthreads();
        if (tid == 0) {
            s_eb = s_le ? atomicAdd(&cnts[3], s_le) : 0u;
            s_nb = s_ln ? atomicAdd(&cnts[0], s_ln) : 0u;
        }
        __syncthreads();
        for (unsigned t = tid; t < s_le; t += NTHR) {
            unsigned p = s_eb + t; if (p < E2CAP) st_wt(&list2[p], stage[t]);
        }
        unsigned ln = s_ln < STGN ? s_ln : STGN;
        for (unsigned t = tid; t < ln; t += NTHR) {
            int s = stageN[t]; unsigned id = s_nb + t;
            if (id < N1CAP) { st_wt(&node1[id], s); st_wt(&idx1[s], (int)id); }
            else st_wt(&idx1[s], -1);
        }
    }
    gbar(bar, 1);

    // ---- phase C: edges into node1 -> list1; node1-only in-deg ----
    {
        if (tid == 0) s_le = 0;
        __syncthreads();
        int base = gid * EPT;
        if (base < NED) {
            #pragma unroll
            for (int c = 0; c < EPT / 4; c++) {
                int4 d4 = *(const int4*)(dst + base + c * 4);
                int dd[4] = {d4.x, d4.y, d4.z, d4.w};
                #pragma unroll
                for (int k = 0; k < 4; k++) {
                    int d = dd[k];
                    if (idx1[d] >= 0) {
                        stage[atomicAdd(&s_le, 1u)] = base + c * 4 + k;
                        if (idx2[d] < 0 && tgt_of(d, tg) < 0) atomicAdd(&incnt[d], 1u);
                        st_wt(&need_out[src[base + c * 4 + k]], (unsigned char)1);
                    }
                }
            }
        }
        __syncthreads();
        if (tid == 0) s_eb = s_le ? atomicAdd(&cnts[2], s_le) : 0u;
        __syncthreads();
        for (unsigned t = tid; t < s_le; t += NTHR) {
            unsigned p = s_eb + t; if (p < E1CAP) st_wt(&list1[p], stage[t]);
        }
    }
    gbar(bar, 2);

    // ---- phase D: filtered out-degree ----
    {
        int base = gid * EPT;
        if (base < NED) {
            #pragma unroll
            for (int c = 0; c < EPT / 4; c++) {
                int4 s4 = *(const int4*)(src + base + c * 4);
                int ss[4] = {s4.x, s4.y, s4.z, s4.w};
                #pragma unroll
                for (int k = 0; k < 4; k++)
                    if (need_out[ss[k]]) atomicAdd(&outcnt[ss[k]], 1u);
            }
        }
    }
    gbar(bar, 3);

    // ---- phase E: agg1 (one 64-lane wave per edge) ----
    {
        unsigned e1 = cnts[2]; if (e1 > E1CAP) e1 = E1CAP;
        int lane = tid & 63;
        unsigned w = (unsigned)gid >> 6;
        const unsigned nw = (NBLK * NTHR) >> 6;
        for (unsigned i = w; i < e1; i += nw) {
            int e = list1[i];
            int s = src[e], d = dst[e];
            int i1 = idx1[d]; if (i1 < 0) continue;
            float wt = ew[e] * rsqrtf(fmaxf((float)outcnt[s], 1.f));
            atomicAdd(&agg1c[(size_t)i1 * F0 + lane], feat[(size_t)s * F0 + lane] * wt);
        }
    }
    gbar(bar, 4);

    // ---- phase F: h1 = relu(in_norm*agg1 @ W1 + b1), 2 nodes per block-iter ----
    {
        unsigned n1 = cnts[0]; if (n1 > N1CAP) n1 = N1CAP;
        int sub = tid >> 7, j = tid & 127;
        unsigned iters = (n1 + NBLK * 2 - 1) / (NBLK * 2);
        for (unsigned it = 0; it < iters; it++) {
            unsigned i = it * NBLK * 2 + blockIdx.x * 2 + sub;
            bool act = i < n1;
            if (act && j < F0) {
                int v = node1[i];
                float innorm = rsqrtf(fmaxf((float)incnt[v], 1.f));
                sa[sub * F0 + j] = agg1c[(size_t)i * F0 + j] * innorm;
            }
            __syncthreads();
            if (act) {
                float acc = b1[j];
                #pragma unroll
                for (int k = 0; k < F0; k++) acc += sa[sub * F0 + k] * W1[k * F1 + j];
                st_wt(&h1c[(size_t)i * F1 + j], fmaxf(acc, 0.f));
            }
            __syncthreads();
        }
    }
    gbar(bar, 5);

    // ---- phase G: agg2 (128-thread group per edge) ----
    {
        unsigned e2 = cnts[3]; if (e2 > E2CAP) e2 = E2CAP;
        int j = tid & 127;
        unsigned grp = (unsigned)gid >> 7;
        const unsigned ng = (NBLK * NTHR) >> 7;
        for (unsigned i = grp; i < e2; i += ng) {
            int e = list2[i];
            int s = src[e], d = dst[e];
            int i1 = idx1[s], i2 = idx2[d];
            if (i1 < 0 || i2 < 0) continue;
            float wt = ew[e] * rsqrtf(fmaxf((float)outcnt[s], 1.f));
            atomicAdd(&agg2c[(size_t)i2 * F1 + j], h1c[(size_t)i1 * F1 + j] * wt);
        }
    }
    gbar(bar, 6);

    // ---- phase H: h2 = relu(in_norm*agg2 @ W2 + b2), 2 nodes per block-iter ----
    {
        unsigned n2 = cnts[1]; if (n2 > N2CAP) n2 = N2CAP;
        int sub = tid >> 7, j = tid & 127;
        unsigned iters = (n2 + NBLK * 2 - 1) / (NBLK * 2);
        for (unsigned it = 0; it < iters; it++) {
            unsigned i = it * NBLK * 2 + blockIdx.x * 2 + sub;
            bool act = i < n2;
            if (act) {
                int v = node2[i];
                float innorm = rsqrtf(fmaxf((float)incnt[v], 1.f));
                sa[sub * F1 + j] = agg2c[(size_t)i * F1 + j] * innorm;
            }
            __syncthreads();
            if (act) {
                float acc = 0.f;
                #pragma unroll 32
                for (int k = 0; k < F1; k++) acc += sa[sub * F1 + k] * W2[k * F1 + j];
                st_wt(&h2c[(size_t)i * F1 + j], fmaxf(acc + b2[j], 0.f));
            }
            __syncthreads();
        }
    }
    gbar(bar, 7);

    // ---- phase I: per-edge (h2 . W3) wave-reduced, atomicAdd into out ----
    {
        unsigned e3 = cnts[4]; if (e3 > E3CAP) e3 = E3CAP;
        int lane = tid & 63;
        unsigned w = (unsigned)gid >> 6;
        const unsigned nw = (NBLK * NTHR) >> 6;
        for (unsigned i = w; i < e3; i += nw) {
            int e = list3[i];
            int s = src[e], d = dst[e];
            int i2 = idx2[s]; if (i2 < 0) continue;
            int g = tgt_of(d, tg);
            float wt = ew[e] * rsqrtf(fmaxf((float)outcnt[s], 1.f))
                             * rsqrtf(fmaxf((float)incnt[d], 1.f));
            float acc0 = 0.f, acc1 = 0.f, acc2 = 0.f, acc3 = 0.f;
            #pragma unroll
            for (int half = 0; half < 2; half++) {
                int j = lane + half * 64;
                float hv = h2c[(size_t)i2 * F1 + j] * wt;
                acc0 += hv * W3[j * NCLS + 0];
                acc1 += hv * W3[j * NCLS + 1];
                acc2 += hv * W3[j * NCLS + 2];
                acc3 += hv * W3[j * NCLS + 3];
            }
            #pragma unroll
            for (int off = 32; off; off >>= 1) {
                acc0 += __shfl_down(acc0, off, 64);
                acc1 += __shfl_down(acc1, off, 64);
                acc2 += __shfl_down(acc2, off, 64);
                acc3 += __shfl_down(acc3, off, 64);
            }
            if (lane == 0) {
                atomicAdd(&out[g * NCLS + 0], acc0);
                atomicAdd(&out[g * NCLS + 1], acc1);
                atomicAdd(&out[g * NCLS + 2], acc2);
                atomicAdd(&out[g * NCLS + 3], acc3);
            }
        }
    }
}

extern "C" void kernel_launch(void* const* d_in, const int* in_sizes, int n_in,
                              void* d_out, int out_size, void* d_ws, size_t ws_size,
                              hipStream_t stream) {
    const float* in_feat = (const float*)d_in[0];
    const float* ew      = (const float*)d_in[1];
    const int*   src     = (const int*)d_in[2];
    const int*   dst     = (const int*)d_in[3];
    const unsigned* bnn  = (const unsigned*)d_in[4];
    const int*   tnode   = (const int*)d_in[5];
    const float* W1 = (const float*)d_in[6];
    const float* b1 = (const float*)d_in[7];
    const float* W2 = (const float*)d_in[8];
    const float* b2 = (const float*)d_in[9];
    const float* W3 = (const float*)d_in[10];
    const float* b3 = (const float*)d_in[11];
    float* out = (float*)d_out;
    (void)in_sizes; (void)n_in; (void)out_size; (void)ws_size;

    char* ws = (char*)d_ws;
    size_t o = 0;
    auto alloc = [&](size_t bytes) { size_t r = o; o += (bytes + 255) & ~(size_t)255; return r; };

    // --- zero-init region (starts at 0) ---
    size_t off_outcnt = alloc((size_t)NND * 4);
    size_t off_incnt  = alloc((size_t)NND * 4);
    size_t off_cnts   = alloc(8 * 4);
    size_t off_bar    = alloc((size_t)NBAR * (NSUB + 1) * 32 * 4);
    size_t off_agg1   = alloc((size_t)N1CAP * F0 * 4);
    size_t off_agg2   = alloc((size_t)N2CAP * F1 * 4);
    size_t off_need   = alloc((size_t)NND);
    size_t zero_bytes = o;
    // --- 0xFF-init region ---
    size_t ff_start = o;
    size_t off_idx2   = alloc((size_t)NND * 4);
    size_t off_idx1   = alloc((size_t)NND * 4);
    size_t ff_bytes = o - ff_start;
    // --- write-before-read region ---
    size_t off_node2   = alloc((size_t)N2CAP * 4);
    size_t off_node1   = alloc((size_t)N1CAP * 4);
    size_t off_list3   = alloc((size_t)E3CAP * 4);
    size_t off_list2   = alloc((size_t)E2CAP * 4);
    size_t off_list1   = alloc((size_t)E1CAP * 4);
    size_t off_h1      = alloc((size_t)N1CAP * F1 * 4);
    size_t off_h2      = alloc((size_t)N2CAP * F1 * 4);

    unsigned* outcnt  = (unsigned*)(ws + off_outcnt);
    unsigned* incnt   = (unsigned*)(ws + off_incnt);
    unsigned* cnts    = (unsigned*)(ws + off_cnts);
    unsigned* bar     = (unsigned*)(ws + off_bar);
    float*    agg1c   = (float*)(ws + off_agg1);
    float*    agg2c   = (float*)(ws + off_agg2);
    unsigned char* need_out = (unsigned char*)(ws + off_need);
    int*      idx2    = (int*)(ws + off_idx2);
    int*      idx1    = (int*)(ws + off_idx1);
    int*      node2   = (int*)(ws + off_node2);
    int*      node1   = (int*)(ws + off_node1);
    int*      list3   = (int*)(ws + off_list3);
    int*      list2   = (int*)(ws + off_list2);
    int*      list1   = (int*)(ws + off_list1);
    float*    h1c     = (float*)(ws + off_h1);
    float*    h2c     = (float*)(ws + off_h2);

    unsigned zw = (unsigned)(zero_bytes / 16);
    unsigned fw = (unsigned)(ff_bytes / 16);
    unsigned iw = zw > fw ? zw : fw;
    k_init<<<(iw + 255) / 256, 256, 0, stream>>>(ws, zw, (unsigned)ff_start, fw);

    k_main<<<NBLK, NTHR, 0, stream>>>(in_feat, ew, src, dst, tnode, bnn,
                                      W1, b1, W2, b2, W3, b3, out,
                                      idx1, idx2, node1, node2,
                                      list1, list2, list3,
                                      cnts, incnt, outcnt, need_out,
                                      agg1c, agg2c, h1c, h2c, bar);
}

// Round 8
// 75.491 us; speedup vs baseline: 7.4255x; 1.0401x over previous
//
#include <hip/hip_runtime.h>

#define NND 50000
#define NED 500000
#define F0 64
#define F1 128
#define NCLS 4
#define NG 8

#define NBLK 256
#define NTHR 1024
#define EPT 2           // NBLK*NTHR*EPT = 524288 >= NED
#define NBAR 8
#define NSUB 8
#define STG 2048        // per-block edge-hit staging (= NTHR*EPT worst case)
#define STGN 2048
#define BMW ((NND + 31) / 32)   // bitmap words

// capacities (expected: n2~80, e3~80, e2~800, n1~800, e1~8000)
#define N1CAP 4096
#define N2CAP 1024
#define E1CAP 32768
#define E2CAP 8192
#define E3CAP 2048

// cnts: [0]=n1 [1]=n2 [2]=e1 [3]=e2 [4]=e3

// write-through store: goes to the coherence point; safe because within this
// kernel no XCD normal-reads a line before its FINAL write (audited per buffer),
// and kernel-boundary flushes handle everything else.
template <typename T>
__device__ __forceinline__ void st_wt(T* p, T v) {
    __hip_atomic_store(p, v, __ATOMIC_RELAXED, __HIP_MEMORY_SCOPE_AGENT);
}

__device__ __forceinline__ bool bt(const unsigned* __restrict__ bm, int n) {
    return (bm[n >> 5] >> (n & 31)) & 1u;
}
__device__ __forceinline__ void bset(unsigned* bm, int n) {
    atomicOr(&bm[n >> 5], 1u << (n & 31));
}

__device__ __forceinline__ void load_targets(const int* __restrict__ tnode,
                                             const unsigned* __restrict__ bnn,
                                             int* t) {
    bool is64 = true;
    #pragma unroll
    for (int k = 0; k < 4; k++) if (bnn[2 * k + 1] != 0u) { is64 = false; break; }
    long long off = 0;
    #pragma unroll
    for (int g = 0; g < NG; g++) {
        t[g] = tnode[g] + (int)off;
        off += is64 ? (long long)bnn[2 * g] : (long long)(int)bnn[g];
    }
}

__device__ __forceinline__ int tgt_of(int d, const int* t) {
    int g = -1;
    #pragma unroll
    for (int k = 0; k < NG; k++) if (d == t[k]) g = k;
    return g;
}

// Fence-free grid barrier (R7-proven): write-through data + vmcnt drain before
// s_barrier; two-level arrival; relaxed-load poll.
__device__ __forceinline__ void gbar(unsigned* bar, int i) {
    asm volatile("s_waitcnt vmcnt(0)" ::: "memory");
    __syncthreads();
    if (threadIdx.x == 0) {
        unsigned* sp = bar + (size_t)(i * (NSUB + 1) + (blockIdx.x & (NSUB - 1))) * 32;
        unsigned* mp = bar + (size_t)(i * (NSUB + 1) + NSUB) * 32;
        unsigned old = __hip_atomic_fetch_add(sp, 1u, __ATOMIC_RELAXED,
                                              __HIP_MEMORY_SCOPE_AGENT);
        if (old + 1u == (unsigned)(NBLK / NSUB))
            __hip_atomic_fetch_add(mp, 1u, __ATOMIC_RELAXED, __HIP_MEMORY_SCOPE_AGENT);
        while (__hip_atomic_load(mp, __ATOMIC_RELAXED, __HIP_MEMORY_SCOPE_AGENT)
               < (unsigned)NSUB)
            __builtin_amdgcn_s_sleep(2);
    }
    __syncthreads();
}

// workspace init: zero region + 0xFF region, 16B stores
__global__ __launch_bounds__(256) void k_init(char* ws, unsigned zw, unsigned foff, unsigned fw) {
    unsigned t = blockIdx.x * blockDim.x + threadIdx.x;
    if (t < zw) ((uint4*)ws)[t] = make_uint4(0u, 0u, 0u, 0u);
    if (t < fw) ((uint4*)(ws + foff))[t] = make_uint4(~0u, ~0u, ~0u, ~0u);
}

__global__ __launch_bounds__(NTHR) void k_main(
        const float* __restrict__ feat, const float* __restrict__ ew,
        const int* __restrict__ src, const int* __restrict__ dst,
        const int* __restrict__ tnode, const unsigned* __restrict__ bnn,
        const float* __restrict__ W1, const float* __restrict__ b1,
        const float* __restrict__ W2, const float* __restrict__ b2,
        const float* __restrict__ W3, const float* __restrict__ b3,
        float* out,
        int* idx1, int* idx2, int* node1, int* node2,
        int* list1, int* list2, int* list3,
        unsigned* cnts, unsigned* incnt, unsigned* outcnt,
        unsigned* bm1, unsigned* bm2, unsigned* bmN,
        float* agg1c, float* agg2c, float* h1c, float* h2c, unsigned* bar) {
    __shared__ unsigned s_le, s_ln, s_eb, s_nb;
    __shared__ int stage[STG];
    __shared__ int stageN[STGN];
    __shared__ float sa[8 * F1];

    const int tid = threadIdx.x;
    const int gid = blockIdx.x * NTHR + tid;
    int tg[NG]; load_targets(tnode, bnn, tg);

    // ---- phase A: edges into targets -> list3; claim node2 (bm2); tgt in-deg ----
    {
        if (tid == 0) { s_le = 0; s_ln = 0; }
        __syncthreads();
        int base = gid * EPT;
        if (base < NED) {
            int2 d2 = *(const int2*)(dst + base);
            int dd[2] = {d2.x, d2.y};
            #pragma unroll
            for (int k = 0; k < 2; k++) {
                int d = dd[k];
                if (tgt_of(d, tg) >= 0) {
                    stage[atomicAdd(&s_le, 1u)] = base + k;
                    atomicAdd(&incnt[d], 1u);
                    int s = src[base + k];
                    bset(bmN, s);
                    if (atomicCAS(&idx2[s], -1, -2) == -1) {
                        bset(bm2, s);
                        unsigned n = atomicAdd(&s_ln, 1u);
                        stageN[n] = s;
                    }
                }
            }
        }
        __syncthreads();
        if (tid == 0) {
            s_eb = s_le ? atomicAdd(&cnts[4], s_le) : 0u;
            s_nb = s_ln ? atomicAdd(&cnts[1], s_ln) : 0u;
        }
        __syncthreads();
        for (unsigned t = tid; t < s_le; t += NTHR) {
            unsigned p = s_eb + t; if (p < E3CAP) st_wt(&list3[p], stage[t]);
        }
        for (unsigned t = tid; t < s_ln; t += NTHR) {
            int s = stageN[t]; unsigned id = s_nb + t;
            if (id < N2CAP) { st_wt(&node2[id], s); st_wt(&idx2[s], (int)id); }
            else st_wt(&idx2[s], -1);
        }
        if (blockIdx.x == 0 && tid < NG * NCLS) st_wt(&out[tid], b3[tid & 3]);
    }
    gbar(bar, 0);

    // ---- phase B: edges into node2 (bm2 test) -> list2; claim node1 (bm1) ----
    {
        if (tid == 0) { s_le = 0; s_ln = 0; }
        __syncthreads();
        int base = gid * EPT;
        if (base < NED) {
            int2 d2 = *(const int2*)(dst + base);
            int dd[2] = {d2.x, d2.y};
            #pragma unroll
            for (int k = 0; k < 2; k++) {
                int d = dd[k];
                if (bt(bm2, d) && idx2[d] >= 0) {
                    stage[atomicAdd(&s_le, 1u)] = base + k;
                    if (tgt_of(d, tg) < 0) atomicAdd(&incnt[d], 1u);
                    int s = src[base + k];
                    bset(bmN, s);
                    if (atomicCAS(&idx1[s], -1, -2) == -1) {
                        bset(bm1, s);
                        unsigned n = atomicAdd(&s_ln, 1u);
                        stageN[n] = s;
                    }
                }
            }
        }
        __syncthreads();
        if (tid == 0) {
            s_eb = s_le ? atomicAdd(&cnts[3], s_le) : 0u;
            s_nb = s_ln ? atomicAdd(&cnts[0], s_ln) : 0u;
        }
        __syncthreads();
        for (unsigned t = tid; t < s_le; t += NTHR) {
            unsigned p = s_eb + t; if (p < E2CAP) st_wt(&list2[p], stage[t]);
        }
        for (unsigned t = tid; t < s_ln; t += NTHR) {
            int s = stageN[t]; unsigned id = s_nb + t;
            if (id < N1CAP) { st_wt(&node1[id], s); st_wt(&idx1[s], (int)id); }
            else st_wt(&idx1[s], -1);
        }
    }
    gbar(bar, 1);

    // ---- phase C: edges into node1 (bm1 test) -> list1; node1-only in-deg ----
    {
        if (tid == 0) s_le = 0;
        __syncthreads();
        int base = gid * EPT;
        if (base < NED) {
            int2 d2 = *(const int2*)(dst + base);
            int dd[2] = {d2.x, d2.y};
            #pragma unroll
            for (int k = 0; k < 2; k++) {
                int d = dd[k];
                if (bt(bm1, d) && idx1[d] >= 0) {
                    stage[atomicAdd(&s_le, 1u)] = base + k;
                    if (idx2[d] < 0 && tgt_of(d, tg) < 0) atomicAdd(&incnt[d], 1u);
                    bset(bmN, src[base + k]);
                }
            }
        }
        __syncthreads();
        if (tid == 0) s_eb = s_le ? atomicAdd(&cnts[2], s_le) : 0u;
        __syncthreads();
        for (unsigned t = tid; t < s_le; t += NTHR) {
            unsigned p = s_eb + t; if (p < E1CAP) st_wt(&list1[p], stage[t]);
        }
    }
    gbar(bar, 2);

    // ---- phase D: filtered out-degree (bmN test) ----
    {
        int base = gid * EPT;
        if (base < NED) {
            int2 s2 = *(const int2*)(src + base);
            int ss[2] = {s2.x, s2.y};
            #pragma unroll
            for (int k = 0; k < 2; k++)
                if (bt(bmN, ss[k])) atomicAdd(&outcnt[ss[k]], 1u);
        }
    }
    gbar(bar, 3);

    // ---- phase E: agg1 (one 64-lane wave per edge) ----
    {
        unsigned e1 = cnts[2]; if (e1 > E1CAP) e1 = E1CAP;
        int lane = tid & 63;
        unsigned w = (unsigned)gid >> 6;
        const unsigned nw = (NBLK * NTHR) >> 6;
        for (unsigned i = w; i < e1; i += nw) {
            int e = list1[i];
            int s = src[e], d = dst[e];
            int i1 = idx1[d]; if (i1 < 0) continue;
            float wt = ew[e] * rsqrtf(fmaxf((float)outcnt[s], 1.f));
            atomicAdd(&agg1c[(size_t)i1 * F0 + lane], feat[(size_t)s * F0 + lane] * wt);
        }
    }
    gbar(bar, 4);

    // ---- phase F: h1 = relu(in_norm*agg1 @ W1 + b1), 8 nodes per block-iter ----
    {
        unsigned n1 = cnts[0]; if (n1 > N1CAP) n1 = N1CAP;
        int sub = tid >> 7, j = tid & 127;
        for (unsigned i0 = blockIdx.x * 8; i0 < n1; i0 += NBLK * 8) {
            unsigned i = i0 + sub;
            bool act = i < n1;
            if (act && j < F0) {
                int v = node1[i];
                float innorm = rsqrtf(fmaxf((float)incnt[v], 1.f));
                sa[sub * F0 + j] = agg1c[(size_t)i * F0 + j] * innorm;
            }
            __syncthreads();
            if (act) {
                float acc = b1[j];
                #pragma unroll
                for (int k = 0; k < F0; k++) acc += sa[sub * F0 + k] * W1[k * F1 + j];
                st_wt(&h1c[(size_t)i * F1 + j], fmaxf(acc, 0.f));
            }
            __syncthreads();
        }
    }
    gbar(bar, 5);

    // ---- phase G: agg2 (128-thread group per edge) ----
    {
        unsigned e2 = cnts[3]; if (e2 > E2CAP) e2 = E2CAP;
        int j = tid & 127;
        unsigned grp = (unsigned)gid >> 7;
        const unsigned ng = (NBLK * NTHR) >> 7;
        for (unsigned i = grp; i < e2; i += ng) {
            int e = list2[i];
            int s = src[e], d = dst[e];
            int i1 = idx1[s], i2 = idx2[d];
            if (i1 < 0 || i2 < 0) continue;
            float wt = ew[e] * rsqrtf(fmaxf((float)outcnt[s], 1.f));
            atomicAdd(&agg2c[(size_t)i2 * F1 + j], h1c[(size_t)i1 * F1 + j] * wt);
        }
    }
    gbar(bar, 6);

    // ---- phase H: h2 = relu(in_norm*agg2 @ W2 + b2), 8 nodes per block-iter ----
    {
        unsigned n2 = cnts[1]; if (n2 > N2CAP) n2 = N2CAP;
        int sub = tid >> 7, j = tid & 127;
        for (unsigned i0 = blockIdx.x * 8; i0 < n2; i0 += NBLK * 8) {
            unsigned i = i0 + sub;
            bool act = i < n2;
            if (act) {
                int v = node2[i];
                float innorm = rsqrtf(fmaxf((float)incnt[v], 1.f));
                sa[sub * F1 + j] = agg2c[(size_t)i * F1 + j] * innorm;
            }
            __syncthreads();
            if (act) {
                float acc = 0.f;
                #pragma unroll 32
                for (int k = 0; k < F1; k++) acc += sa[sub * F1 + k] * W2[k * F1 + j];
                st_wt(&h2c[(size_t)i * F1 + j], fmaxf(acc + b2[j], 0.f));
            }
            __syncthreads();
        }
    }
    gbar(bar, 7);

    // ---- phase I: per-edge (h2 . W3) wave-reduced, atomicAdd into out ----
    {
        unsigned e3 = cnts[4]; if (e3 > E3CAP) e3 = E3CAP;
        int lane = tid & 63;
        unsigned w = (unsigned)gid >> 6;
        const unsigned nw = (NBLK * NTHR) >> 6;
        for (unsigned i = w; i < e3; i += nw) {
            int e = list3[i];
            int s = src[e], d = dst[e];
            int i2 = idx2[s]; if (i2 < 0) continue;
            int g = tgt_of(d, tg);
            float wt = ew[e] * rsqrtf(fmaxf((float)outcnt[s], 1.f))
                             * rsqrtf(fmaxf((float)incnt[d], 1.f));
            float acc0 = 0.f, acc1 = 0.f, acc2 = 0.f, acc3 = 0.f;
            #pragma unroll
            for (int half = 0; half < 2; half++) {
                int j = lane + half * 64;
                float hv = h2c[(size_t)i2 * F1 + j] * wt;
                acc0 += hv * W3[j * NCLS + 0];
                acc1 += hv * W3[j * NCLS + 1];
                acc2 += hv * W3[j * NCLS + 2];
                acc3 += hv * W3[j * NCLS + 3];
            }
            #pragma unroll
            for (int off = 32; off; off >>= 1) {
                acc0 += __shfl_down(acc0, off, 64);
                acc1 += __shfl_down(acc1, off, 64);
                acc2 += __shfl_down(acc2, off, 64);
                acc3 += __shfl_down(acc3, off, 64);
            }
            if (lane == 0) {
                atomicAdd(&out[g * NCLS + 0], acc0);
                atomicAdd(&out[g * NCLS + 1], acc1);
                atomicAdd(&out[g * NCLS + 2], acc2);
                atomicAdd(&out[g * NCLS + 3], acc3);
            }
        }
    }
}

extern "C" void kernel_launch(void* const* d_in, const int* in_sizes, int n_in,
                              void* d_out, int out_size, void* d_ws, size_t ws_size,
                              hipStream_t stream) {
    const float* in_feat = (const float*)d_in[0];
    const float* ew      = (const float*)d_in[1];
    const int*   src     = (const int*)d_in[2];
    const int*   dst     = (const int*)d_in[3];
    const unsigned* bnn  = (const unsigned*)d_in[4];
    const int*   tnode   = (const int*)d_in[5];
    const float* W1 = (const float*)d_in[6];
    const float* b1 = (const float*)d_in[7];
    const float* W2 = (const float*)d_in[8];
    const float* b2 = (const float*)d_in[9];
    const float* W3 = (const float*)d_in[10];
    const float* b3 = (const float*)d_in[11];
    float* out = (float*)d_out;
    (void)in_sizes; (void)n_in; (void)out_size; (void)ws_size;

    char* ws = (char*)d_ws;
    size_t o = 0;
    auto alloc = [&](size_t bytes) { size_t r = o; o += (bytes + 255) & ~(size_t)255; return r; };

    // --- zero-init region (starts at 0) ---
    size_t off_outcnt = alloc((size_t)NND * 4);
    size_t off_incnt  = alloc((size_t)NND * 4);
    size_t off_cnts   = alloc(8 * 4);
    size_t off_bar    = alloc((size_t)NBAR * (NSUB + 1) * 32 * 4);
    size_t off_bm1    = alloc((size_t)BMW * 4);
    size_t off_bm2    = alloc((size_t)BMW * 4);
    size_t off_bmN    = alloc((size_t)BMW * 4);
    size_t off_agg1   = alloc((size_t)N1CAP * F0 * 4);
    size_t off_agg2   = alloc((size_t)N2CAP * F1 * 4);
    size_t zero_bytes = o;
    // --- 0xFF-init region ---
    size_t ff_start = o;
    size_t off_idx2   = alloc((size_t)NND * 4);
    size_t off_idx1   = alloc((size_t)NND * 4);
    size_t ff_bytes = o - ff_start;
    // --- write-before-read region ---
    size_t off_node2   = alloc((size_t)N2CAP * 4);
    size_t off_node1   = alloc((size_t)N1CAP * 4);
    size_t off_list3   = alloc((size_t)E3CAP * 4);
    size_t off_list2   = alloc((size_t)E2CAP * 4);
    size_t off_list1   = alloc((size_t)E1CAP * 4);
    size_t off_h1      = alloc((size_t)N1CAP * F1 * 4);
    size_t off_h2      = alloc((size_t)N2CAP * F1 * 4);

    unsigned* outcnt  = (unsigned*)(ws + off_outcnt);
    unsigned* incnt   = (unsigned*)(ws + off_incnt);
    unsigned* cnts    = (unsigned*)(ws + off_cnts);
    unsigned* bar     = (unsigned*)(ws + off_bar);
    unsigned* bm1     = (unsigned*)(ws + off_bm1);
    unsigned* bm2     = (unsigned*)(ws + off_bm2);
    unsigned* bmN     = (unsigned*)(ws + off_bmN);
    float*    agg1c   = (float*)(ws + off_agg1);
    float*    agg2c   = (float*)(ws + off_agg2);
    int*      idx2    = (int*)(ws + off_idx2);
    int*      idx1    = (int*)(ws + off_idx1);
    int*      node2   = (int*)(ws + off_node2);
    int*      node1   = (int*)(ws + off_node1);
    int*      list3   = (int*)(ws + off_list3);
    int*      list2   = (int*)(ws + off_list2);
    int*      list1   = (int*)(ws + off_list1);
    float*    h1c     = (float*)(ws + off_h1);
    float*    h2c     = (float*)(ws + off_h2);

    unsigned zw = (unsigned)(zero_bytes / 16);
    unsigned fw = (unsigned)(ff_bytes / 16);
    unsigned iw = zw > fw ? zw : fw;
    k_init<<<(iw + 255) / 256, 256, 0, stream>>>(ws, zw, (unsigned)ff_start, fw);

    k_main<<<NBLK, NTHR, 0, stream>>>(in_feat, ew, src, dst, tnode, bnn,
                                      W1, b1, W2, b2, W3, b3, out,
                                      idx1, idx2, node1, node2,
                                      list1, list2, list3,
                                      cnts, incnt, outcnt, bm1, bm2, bmN,
                                      agg1c, agg2c, h1c, h2c, bar);
}

// Round 9
// 61.872 us; speedup vs baseline: 9.0600x; 1.2201x over previous
//
#include <hip/hip_runtime.h>

#define NND 50000
#define NED 500000
#define F0 64
#define F1 128
#define NCLS 4
#define NG 8

#define NBLK 256
#define NTHR 1024
#define EPT 2           // NBLK*NTHR*EPT = 524288 >= NED
#define NBAR 8
#define NSUB 8
#define STG 2048        // per-block edge-hit staging (= NTHR*EPT worst case)
#define STGN 2048
#define BMW ((NND + 31) / 32)
#define EMASK 0x7FFFFu  // e < 2^19 (NED=500000 < 524288)

// capacities (expected: n2~80, e3~80, e2~800, n1~800, e1~8000)
#define N1CAP 4096
#define N2CAP 1024
#define E1CAP 32768
#define E2CAP 8192
#define E3CAP 2048

// cnts: [0]=n1 [1]=n2 [2]=e1 [3]=e2 [4]=e3

// write-through store: lands at the coherence point; safe because no XCD
// normal-reads a line before its FINAL write (audited per buffer), and
// kernel-boundary flushes cover everything else.
template <typename T>
__device__ __forceinline__ void st_wt(T* p, T v) {
    __hip_atomic_store(p, v, __ATOMIC_RELAXED, __HIP_MEMORY_SCOPE_AGENT);
}

__device__ __forceinline__ bool bt(const unsigned* __restrict__ bm, int n) {
    return (bm[n >> 5] >> (n & 31)) & 1u;
}
__device__ __forceinline__ void bset(unsigned* bm, int n) {
    atomicOr(&bm[n >> 5], 1u << (n & 31));
}

__device__ __forceinline__ void load_targets(const int* __restrict__ tnode,
                                             const unsigned* __restrict__ bnn,
                                             int* t) {
    bool is64 = true;
    #pragma unroll
    for (int k = 0; k < 4; k++) if (bnn[2 * k + 1] != 0u) { is64 = false; break; }
    long long off = 0;
    #pragma unroll
    for (int g = 0; g < NG; g++) {
        t[g] = tnode[g] + (int)off;
        off += is64 ? (long long)bnn[2 * g] : (long long)(int)bnn[g];
    }
}

__device__ __forceinline__ int tgt_of(int d, const int* t) {
    int g = -1;
    #pragma unroll
    for (int k = 0; k < NG; k++) if (d == t[k]) g = k;
    return g;
}

// Fence-free grid barrier (R7/R8-proven): write-through data + vmcnt drain
// before s_barrier; two-level arrival; relaxed-load poll.
__device__ __forceinline__ void gbar(unsigned* bar, int i) {
    asm volatile("s_waitcnt vmcnt(0)" ::: "memory");
    __syncthreads();
    if (threadIdx.x == 0) {
        unsigned* sp = bar + (size_t)(i * (NSUB + 1) + (blockIdx.x & (NSUB - 1))) * 32;
        unsigned* mp = bar + (size_t)(i * (NSUB + 1) + NSUB) * 32;
        unsigned old = __hip_atomic_fetch_add(sp, 1u, __ATOMIC_RELAXED,
                                              __HIP_MEMORY_SCOPE_AGENT);
        if (old + 1u == (unsigned)(NBLK / NSUB))
            __hip_atomic_fetch_add(mp, 1u, __ATOMIC_RELAXED, __HIP_MEMORY_SCOPE_AGENT);
        while (__hip_atomic_load(mp, __ATOMIC_RELAXED, __HIP_MEMORY_SCOPE_AGENT)
               < (unsigned)NSUB)
            __builtin_amdgcn_s_sleep(1);
    }
    __syncthreads();
}

// workspace init: zero region + 0xFF region, 16B stores
__global__ __launch_bounds__(256) void k_init(char* ws, unsigned zw, unsigned foff, unsigned fw) {
    unsigned t = blockIdx.x * blockDim.x + threadIdx.x;
    if (t < zw) ((uint4*)ws)[t] = make_uint4(0u, 0u, 0u, 0u);
    if (t < fw) ((uint4*)(ws + foff))[t] = make_uint4(~0u, ~0u, ~0u, ~0u);
}

__global__ __launch_bounds__(NTHR) void k_main(
        const float* __restrict__ feat, const float* __restrict__ ew,
        const int* __restrict__ src, const int* __restrict__ dst,
        const int* __restrict__ tnode, const unsigned* __restrict__ bnn,
        const float* __restrict__ W1, const float* __restrict__ b1,
        const float* __restrict__ W2, const float* __restrict__ b2,
        const float* __restrict__ W3, const float* __restrict__ b3,
        float* out,
        int* idx1, int* idx2,
        unsigned* list1, unsigned* list2, unsigned* list3,
        unsigned* cnts, unsigned* incnt, unsigned* outcnt,
        unsigned* bm1, unsigned* bm2, unsigned* bmN,
        float* agg1c, float* agg2c, unsigned* bar) {
    __shared__ unsigned s_le, s_ln, s_eb, s_nb;
    __shared__ unsigned stage[STG];
    __shared__ int stageN[STGN];

    const int tid = threadIdx.x;
    const int gid = blockIdx.x * NTHR + tid;
    const int lane = tid & 63;
    int tg[NG]; load_targets(tnode, bnn, tg);

    // ---- phase A: edges into targets -> list3 {g|e}; claim node2; tgt in-deg ----
    {
        if (tid == 0) { s_le = 0; s_ln = 0; }
        __syncthreads();
        int base = gid * EPT;
        if (base < NED) {
            int2 d2 = *(const int2*)(dst + base);
            int dd[2] = {d2.x, d2.y};
            #pragma unroll
            for (int k = 0; k < 2; k++) {
                int d = dd[k];
                int g = tgt_of(d, tg);
                if (g >= 0) {
                    int e = base + k;
                    stage[atomicAdd(&s_le, 1u)] = ((unsigned)g << 19) | (unsigned)e;
                    atomicAdd(&incnt[d], 1u);
                    int s = src[e];
                    bset(bmN, s);
                    if (atomicCAS(&idx2[s], -1, -2) == -1) {
                        bset(bm2, s);
                        stageN[atomicAdd(&s_ln, 1u)] = s;
                    }
                }
            }
        }
        __syncthreads();
        if (tid == 0) {
            s_eb = s_le ? atomicAdd(&cnts[4], s_le) : 0u;
            s_nb = s_ln ? atomicAdd(&cnts[1], s_ln) : 0u;
        }
        __syncthreads();
        for (unsigned t = tid; t < s_le; t += NTHR) {
            unsigned p = s_eb + t; if (p < E3CAP) st_wt(&list3[p], stage[t]);
        }
        for (unsigned t = tid; t < s_ln; t += NTHR) {
            int s = stageN[t]; unsigned id = s_nb + t;
            st_wt(&idx2[s], id < N2CAP ? (int)id : -1);
        }
        if (blockIdx.x == 0 && tid < NG * NCLS) st_wt(&out[tid], b3[tid & 3]);
    }
    gbar(bar, 0);

    // ---- phase B: edges into node2 -> list2 {i2|e}; claim node1 ----
    {
        if (tid == 0) { s_le = 0; s_ln = 0; }
        __syncthreads();
        int base = gid * EPT;
        if (base < NED) {
            int2 d2 = *(const int2*)(dst + base);
            int dd[2] = {d2.x, d2.y};
            #pragma unroll
            for (int k = 0; k < 2; k++) {
                int d = dd[k];
                if (bt(bm2, d)) {
                    int iv = idx2[d];
                    if (iv >= 0) {
                        int e = base + k;
                        stage[atomicAdd(&s_le, 1u)] = ((unsigned)iv << 19) | (unsigned)e;
                        if (tgt_of(d, tg) < 0) atomicAdd(&incnt[d], 1u);
                        int s = src[e];
                        bset(bmN, s);
                        if (atomicCAS(&idx1[s], -1, -2) == -1) {
                            bset(bm1, s);
                            stageN[atomicAdd(&s_ln, 1u)] = s;
                        }
                    }
                }
            }
        }
        __syncthreads();
        if (tid == 0) {
            s_eb = s_le ? atomicAdd(&cnts[3], s_le) : 0u;
            s_nb = s_ln ? atomicAdd(&cnts[0], s_ln) : 0u;
        }
        __syncthreads();
        for (unsigned t = tid; t < s_le; t += NTHR) {
            unsigned p = s_eb + t; if (p < E2CAP) st_wt(&list2[p], stage[t]);
        }
        for (unsigned t = tid; t < s_ln; t += NTHR) {
            int s = stageN[t]; unsigned id = s_nb + t;
            st_wt(&idx1[s], id < N1CAP ? (int)id : -1);
        }
    }
    gbar(bar, 1);

    // ---- phase C: edges into node1 -> list1 {i1|e}; node1-only in-deg ----
    {
        if (tid == 0) s_le = 0;
        __syncthreads();
        int base = gid * EPT;
        if (base < NED) {
            int2 d2 = *(const int2*)(dst + base);
            int dd[2] = {d2.x, d2.y};
            #pragma unroll
            for (int k = 0; k < 2; k++) {
                int d = dd[k];
                if (bt(bm1, d)) {
                    int iv = idx1[d];
                    if (iv >= 0) {
                        int e = base + k;
                        stage[atomicAdd(&s_le, 1u)] = ((unsigned)iv << 19) | (unsigned)e;
                        if (idx2[d] < 0 && tgt_of(d, tg) < 0) atomicAdd(&incnt[d], 1u);
                        bset(bmN, src[e]);
                    }
                }
            }
        }
        __syncthreads();
        if (tid == 0) s_eb = s_le ? atomicAdd(&cnts[2], s_le) : 0u;
        __syncthreads();
        for (unsigned t = tid; t < s_le; t += NTHR) {
            unsigned p = s_eb + t; if (p < E1CAP) st_wt(&list1[p], stage[t]);
        }
    }
    gbar(bar, 2);

    // ---- phase D: filtered out-degree (bmN test) ----
    {
        int base = gid * EPT;
        if (base < NED) {
            int2 s2 = *(const int2*)(src + base);
            int ss[2] = {s2.x, s2.y};
            #pragma unroll
            for (int k = 0; k < 2; k++)
                if (bt(bmN, ss[k])) atomicAdd(&outcnt[ss[k]], 1u);
        }
    }
    gbar(bar, 3);

    // ---- phase E: agg1 (wave per edge, packed list, 2-way ILP) ----
    {
        unsigned e1 = cnts[2]; if (e1 > E1CAP) e1 = E1CAP;
        unsigned w = (unsigned)gid >> 6;
        const unsigned nw = (NBLK * NTHR) >> 6;
        for (unsigned i = w; i < e1; i += 2 * nw) {
            unsigned pk0 = list1[i];
            unsigned j2 = i + nw;
            unsigned pk1 = (j2 < e1) ? list1[j2] : 0u;
            int e0 = pk0 & EMASK, i10 = pk0 >> 19;
            float we0 = ew[e0]; int s0 = src[e0];
            int e1i = pk1 & EMASK, i11 = pk1 >> 19;
            float we1 = 0.f; int s1 = 0;
            if (j2 < e1) { we1 = ew[e1i]; s1 = src[e1i]; }
            float wt0 = we0 * rsqrtf(fmaxf((float)outcnt[s0], 1.f));
            atomicAdd(&agg1c[(size_t)i10 * F0 + lane],
                      feat[(size_t)s0 * F0 + lane] * wt0);
            if (j2 < e1) {
                float wt1 = we1 * rsqrtf(fmaxf((float)outcnt[s1], 1.f));
                atomicAdd(&agg1c[(size_t)i11 * F0 + lane],
                          feat[(size_t)s1 * F0 + lane] * wt1);
            }
        }
    }
    gbar(bar, 4);

    // ---- phase G': agg2 with h1 computed on the fly (wave per edge) ----
    {
        unsigned e2 = cnts[3]; if (e2 > E2CAP) e2 = E2CAP;
        unsigned w = (unsigned)gid >> 6;
        const unsigned nw = (NBLK * NTHR) >> 6;
        for (unsigned i = w; i < e2; i += nw) {
            unsigned pk = list2[i];
            int e = pk & EMASK, i2 = pk >> 19;
            float we = ew[e]; int s = src[e];
            int i1 = idx1[s]; if (i1 < 0) continue;
            float wt = we * rsqrtf(fmaxf((float)outcnt[s], 1.f));
            float innorm1 = rsqrtf(fmaxf((float)incnt[s], 1.f));
            float rv = agg1c[(size_t)i1 * F0 + lane];
            float acc0 = 0.f, acc1 = 0.f;
            #pragma unroll 8
            for (int k2 = 0; k2 < F0; k2++) {
                float bv = __shfl(rv, k2, 64);
                acc0 += bv * W1[k2 * F1 + lane];
                acc1 += bv * W1[k2 * F1 + lane + 64];
            }
            float h0 = fmaxf(acc0 * innorm1 + b1[lane], 0.f) * wt;
            float h1v = fmaxf(acc1 * innorm1 + b1[lane + 64], 0.f) * wt;
            atomicAdd(&agg2c[(size_t)i2 * F1 + lane], h0);
            atomicAdd(&agg2c[(size_t)i2 * F1 + lane + 64], h1v);
        }
    }
    gbar(bar, 5);

    // ---- phase I': out += (h2-on-the-fly . W3) per e3-edge (wave per edge) ----
    {
        unsigned e3 = cnts[4]; if (e3 > E3CAP) e3 = E3CAP;
        unsigned w = (unsigned)gid >> 6;
        const unsigned nw = (NBLK * NTHR) >> 6;
        for (unsigned i = w; i < e3; i += nw) {
            unsigned pk = list3[i];
            int e = pk & EMASK, g = pk >> 19;
            float we = ew[e]; int s = src[e];
            int i2 = idx2[s]; if (i2 < 0) continue;
            float wt = we * rsqrtf(fmaxf((float)outcnt[s], 1.f))
                          * rsqrtf(fmaxf((float)incnt[tg[g]], 1.f));
            float innorm2 = rsqrtf(fmaxf((float)incnt[s], 1.f));
            float rv0 = agg2c[(size_t)i2 * F1 + lane];
            float rv1 = agg2c[(size_t)i2 * F1 + lane + 64];
            float acc0 = 0.f, acc1 = 0.f;
            #pragma unroll 8
            for (int k2 = 0; k2 < 64; k2++) {
                float bv = __shfl(rv0, k2, 64);
                acc0 += bv * W2[k2 * F1 + lane];
                acc1 += bv * W2[k2 * F1 + lane + 64];
            }
            #pragma unroll 8
            for (int k2 = 0; k2 < 64; k2++) {
                float bv = __shfl(rv1, k2, 64);
                acc0 += bv * W2[(k2 + 64) * F1 + lane];
                acc1 += bv * W2[(k2 + 64) * F1 + lane + 64];
            }
            float h20 = fmaxf(acc0 * innorm2 + b2[lane], 0.f);
            float h21 = fmaxf(acc1 * innorm2 + b2[lane + 64], 0.f);
            float oc0 = (h20 * W3[lane * NCLS + 0] + h21 * W3[(lane + 64) * NCLS + 0]) * wt;
            float oc1 = (h20 * W3[lane * NCLS + 1] + h21 * W3[(lane + 64) * NCLS + 1]) * wt;
            float oc2 = (h20 * W3[lane * NCLS + 2] + h21 * W3[(lane + 64) * NCLS + 2]) * wt;
            float oc3 = (h20 * W3[lane * NCLS + 3] + h21 * W3[(lane + 64) * NCLS + 3]) * wt;
            #pragma unroll
            for (int off = 32; off; off >>= 1) {
                oc0 += __shfl_down(oc0, off, 64);
                oc1 += __shfl_down(oc1, off, 64);
                oc2 += __shfl_down(oc2, off, 64);
                oc3 += __shfl_down(oc3, off, 64);
            }
            if (lane == 0) {
                atomicAdd(&out[g * NCLS + 0], oc0);
                atomicAdd(&out[g * NCLS + 1], oc1);
                atomicAdd(&out[g * NCLS + 2], oc2);
                atomicAdd(&out[g * NCLS + 3], oc3);
            }
        }
    }
}

extern "C" void kernel_launch(void* const* d_in, const int* in_sizes, int n_in,
                              void* d_out, int out_size, void* d_ws, size_t ws_size,
                              hipStream_t stream) {
    const float* in_feat = (const float*)d_in[0];
    const float* ew      = (const float*)d_in[1];
    const int*   src     = (const int*)d_in[2];
    const int*   dst     = (const int*)d_in[3];
    const unsigned* bnn  = (const unsigned*)d_in[4];
    const int*   tnode   = (const int*)d_in[5];
    const float* W1 = (const float*)d_in[6];
    const float* b1 = (const float*)d_in[7];
    const float* W2 = (const float*)d_in[8];
    const float* b2 = (const float*)d_in[9];
    const float* W3 = (const float*)d_in[10];
    const float* b3 = (const float*)d_in[11];
    float* out = (float*)d_out;
    (void)in_sizes; (void)n_in; (void)out_size; (void)ws_size;

    char* ws = (char*)d_ws;
    size_t o = 0;
    auto alloc = [&](size_t bytes) { size_t r = o; o += (bytes + 255) & ~(size_t)255; return r; };

    // --- zero-init region (starts at 0) ---
    size_t off_outcnt = alloc((size_t)NND * 4);
    size_t off_incnt  = alloc((size_t)NND * 4);
    size_t off_cnts   = alloc(8 * 4);
    size_t off_bar    = alloc((size_t)NBAR * (NSUB + 1) * 32 * 4);
    size_t off_bm1    = alloc((size_t)BMW * 4);
    size_t off_bm2    = alloc((size_t)BMW * 4);
    size_t off_bmN    = alloc((size_t)BMW * 4);
    size_t off_agg1   = alloc((size_t)N1CAP * F0 * 4);
    size_t off_agg2   = alloc((size_t)N2CAP * F1 * 4);
    size_t zero_bytes = o;
    // --- 0xFF-init region ---
    size_t ff_start = o;
    size_t off_idx2   = alloc((size_t)NND * 4);
    size_t off_idx1   = alloc((size_t)NND * 4);
    size_t ff_bytes = o - ff_start;
    // --- write-before-read region ---
    size_t off_list3   = alloc((size_t)E3CAP * 4);
    size_t off_list2   = alloc((size_t)E2CAP * 4);
    size_t off_list1   = alloc((size_t)E1CAP * 4);

    unsigned* outcnt  = (unsigned*)(ws + off_outcnt);
    unsigned* incnt   = (unsigned*)(ws + off_incnt);
    unsigned* cnts    = (unsigned*)(ws + off_cnts);
    unsigned* bar     = (unsigned*)(ws + off_bar);
    unsigned* bm1     = (unsigned*)(ws + off_bm1);
    unsigned* bm2     = (unsigned*)(ws + off_bm2);
    unsigned* bmN     = (unsigned*)(ws + off_bmN);
    float*    agg1c   = (float*)(ws + off_agg1);
    float*    agg2c   = (float*)(ws + off_agg2);
    int*      idx2    = (int*)(ws + off_idx2);
    int*      idx1    = (int*)(ws + off_idx1);
    unsigned* list3   = (unsigned*)(ws + off_list3);
    unsigned* list2   = (unsigned*)(ws + off_list2);
    unsigned* list1   = (unsigned*)(ws + off_list1);

    unsigned zw = (unsigned)(zero_bytes / 16);
    unsigned fw = (unsigned)(ff_bytes / 16);
    unsigned iw = zw > fw ? zw : fw;
    k_init<<<(iw + 255) / 256, 256, 0, stream>>>(ws, zw, (unsigned)ff_start, fw);

    k_main<<<NBLK, NTHR, 0, stream>>>(in_feat, ew, src, dst, tnode, bnn,
                                      W1, b1, W2, b2, W3, b3, out,
                                      idx1, idx2, list1, list2, list3,
                                      cnts, incnt, outcnt, bm1, bm2, bmN,
                                      agg1c, agg2c, bar);
}